// Round 1
// baseline (343.445 us; speedup 1.0000x reference)
//
#include <hip/hip_runtime.h>
#include <hip/hip_bf16.h>

typedef _Float16 f16x8 __attribute__((ext_vector_type(8)));
typedef float f32x4 __attribute__((ext_vector_type(4)));

#define B_SZ 64
#define T_SZ 2048
#define D_SZ 300
#define M_SZ (B_SZ * T_SZ)      // 131072
#define KP 320                   // padded K
#define NP 640                   // padded combined N (z: 0..299, o: 320..619)
#define NCHUNK 16
#define CLEN 128                 // T / NCHUNK

__device__ __forceinline__ void gld_lds16(const void* g, void* l) {
    __builtin_amdgcn_global_load_lds(
        (const __attribute__((address_space(1))) unsigned int*)g,
        (__attribute__((address_space(3))) unsigned int*)l,
        16, 0, 0);
}

__device__ __forceinline__ float fast_tanh(float x) {
    float e = __expf(2.0f * x);
    return 1.0f - 2.0f * __builtin_amdgcn_rcpf(e + 1.0f);
}

// ---- pack inputs_encoding fp32 [M,300] -> fp16 [M,320] zero-padded ----
__global__ void pack_x(const float* __restrict__ in, _Float16* __restrict__ out) {
    unsigned int i = blockIdx.x * 256u + threadIdx.x;   // grid covers M*KP exactly
    unsigned int row = i / KP;
    unsigned int k = i - row * KP;
    float v = (k < D_SZ) ? in[(size_t)row * D_SZ + k] : 0.0f;
    out[i] = (_Float16)v;
}

// ---- pack Wz/Wo fp32 [300,300] -> combined fp16 [640,320]: row n holds W[n][k] ----
__global__ void pack_w(const float* __restrict__ Wz, const float* __restrict__ Wo,
                       _Float16* __restrict__ W) {
    unsigned int i = blockIdx.x * 256u + threadIdx.x;
    if (i >= NP * KP) return;
    unsigned int n = i / KP;
    unsigned int k = i - n * KP;
    float v = 0.0f;
    if (k < D_SZ) {
        if (n < D_SZ) v = Wz[n * D_SZ + k];
        else if (n >= 320 && n < 320 + D_SZ) v = Wo[(n - 320) * D_SZ + k];
    }
    W[i] = (_Float16)v;
}

__global__ void pack_bias(const float* __restrict__ bz, const float* __restrict__ bo,
                          float* __restrict__ bias) {
    int n = threadIdx.x;
    float v = 0.0f;
    if (n < D_SZ) v = bz[n];
    else if (n >= 320 && n < 320 + D_SZ) v = bo[n - 320];
    bias[n] = v;
}

// ---- GEMM: C16[m][n] = tanh( sum_k X[m][k]*W[n][k] + bias[n] ), fp16 out ----
// 128x128 tile, BK=32, 4 waves (2x2), 16x16x32 f16 MFMA, double-buffered LDS via
// global_load_lds; XOR swizzle unit ^= (row>>1)&3 on both source and read.
__global__ __launch_bounds__(256) void gemm_zo(const _Float16* __restrict__ X,
                                               const _Float16* __restrict__ W,
                                               const float* __restrict__ bias,
                                               _Float16* __restrict__ C) {
    __shared__ _Float16 As[2][128 * 32];
    __shared__ _Float16 Bs[2][128 * 32];

    const int tid = threadIdx.x;
    const int lane = tid & 63;
    const int wid = tid >> 6;
    const int wm = wid >> 1, wn = wid & 1;

    // XCD-aware swizzle (5120 blocks, 5120 % 8 == 0 -> bijective)
    int g = blockIdx.x;
    int s = (g & 7) * (5120 / 8) + (g >> 3);
    int bm = s / 5;          // 1024 M-tiles
    int bn = s - bm * 5;     // 5 N-tiles

    f32x4 acc[4][4] = {};

    const int r_in_c = lane >> 2;          // row within 16-row chunk
    const int u_phys = lane & 3;           // 16B unit within 64B row

    auto stage = [&](int buf, int kt) {
#pragma unroll
        for (int j = 0; j < 2; ++j) {
            int c = wid + j * 4;           // chunk 0..7
            int row = c * 16 + r_in_c;
            int ul = u_phys ^ ((row >> 1) & 3);   // inverse-swizzled source unit
            const _Float16* ga = X + ((size_t)(bm * 128 + row) * KP + kt * 32 + ul * 8);
            gld_lds16(ga, &As[buf][c * 512]);
            const _Float16* gb = W + ((size_t)(bn * 128 + row) * KP + kt * 32 + ul * 8);
            gld_lds16(gb, &Bs[buf][c * 512]);
        }
    };

    stage(0, 0);
    __syncthreads();

    int buf = 0;
#pragma unroll 1
    for (int kt = 0; kt < 10; ++kt) {
        if (kt < 9) stage(buf ^ 1, kt + 1);

        f16x8 af[4], bf[4];
#pragma unroll
        for (int ms = 0; ms < 4; ++ms) {
            int row = wm * 64 + ms * 16 + (lane & 15);
            int u = (lane >> 4) ^ ((row >> 1) & 3);
            af[ms] = *(const f16x8*)&As[buf][row * 32 + u * 8];
        }
#pragma unroll
        for (int ns = 0; ns < 4; ++ns) {
            int row = wn * 64 + ns * 16 + (lane & 15);
            int u = (lane >> 4) ^ ((row >> 1) & 3);
            bf[ns] = *(const f16x8*)&Bs[buf][row * 32 + u * 8];
        }
#pragma unroll
        for (int ms = 0; ms < 4; ++ms)
#pragma unroll
            for (int ns = 0; ns < 4; ++ns)
                acc[ms][ns] = __builtin_amdgcn_mfma_f32_16x16x32_f16(af[ms], bf[ns], acc[ms][ns], 0, 0, 0);

        __syncthreads();
        buf ^= 1;
    }

    // epilogue: bias + tanh, store fp16
    const int mrow0 = bm * 128 + wm * 64;
    const int ncol0 = bn * 128 + wn * 64;
#pragma unroll
    for (int ns = 0; ns < 4; ++ns) {
        int n = ncol0 + ns * 16 + (lane & 15);
        float bv = bias[n];
#pragma unroll
        for (int ms = 0; ms < 4; ++ms) {
            int m0 = mrow0 + ms * 16 + (lane >> 4) * 4;
#pragma unroll
            for (int r = 0; r < 4; ++r) {
                float v = fast_tanh(acc[ms][ns][r] + bv);
                C[(size_t)(m0 + r) * NP + n] = (_Float16)v;
            }
        }
    }
}

// ---- scan phase 1: per (b, chunk, d) compute affine (A = prod g, Bc) ----
__global__ void scan_p1(const float* __restrict__ gate, const _Float16* __restrict__ C,
                        float* __restrict__ Aout, float* __restrict__ Bout) {
    int b = blockIdx.x >> 4;
    int nc = blockIdx.x & 15;
    int d = threadIdx.x;
    if (d >= D_SZ) return;
    size_t base = (size_t)b * T_SZ + (size_t)nc * CLEN;
    const float* gp = gate + base * D_SZ + d;
    const _Float16* zp = C + base * NP + d;
    float A = 1.0f, Bc = 0.0f;
    for (int t = 0; t < CLEN; ++t) {
        float gv = gp[(size_t)t * D_SZ];
        float zv = (float)zp[(size_t)t * NP];
        A *= gv;
        Bc = gv * Bc + (1.0f - gv) * zv;
    }
    int o = (b * NCHUNK + nc) * D_SZ + d;
    Aout[o] = A;
    Bout[o] = Bc;
}

// ---- scan phase 2: sequential scan over the 16 chunk summaries ----
__global__ void scan_p2(const float* __restrict__ A, const float* __restrict__ Bc,
                        float* __restrict__ Cin) {
    int idx = blockIdx.x * 256 + threadIdx.x;
    if (idx >= B_SZ * D_SZ) return;
    int b = idx / D_SZ;
    int d = idx - b * D_SZ;
    float c = 0.0f;
    for (int nc = 0; nc < NCHUNK; ++nc) {
        int o = (b * NCHUNK + nc) * D_SZ + d;
        Cin[o] = c;
        c = A[o] * c + Bc[o];
    }
}

// ---- scan phase 3: replay chunk with correct c_in, write h = o * c ----
__global__ void scan_p3(const float* __restrict__ gate, const _Float16* __restrict__ C,
                        const float* __restrict__ Cin, float* __restrict__ out) {
    int b = blockIdx.x >> 4;
    int nc = blockIdx.x & 15;
    int d = threadIdx.x;
    if (d >= D_SZ) return;
    size_t base = (size_t)b * T_SZ + (size_t)nc * CLEN;
    const float* gp = gate + base * D_SZ + d;
    const _Float16* zp = C + base * NP + d;
    const _Float16* op = zp + 320;
    float* hp = out + base * D_SZ + d;
    float c = Cin[(b * NCHUNK + nc) * D_SZ + d];
    for (int t = 0; t < CLEN; ++t) {
        float gv = gp[(size_t)t * D_SZ];
        float zv = (float)zp[(size_t)t * NP];
        float ov = (float)op[(size_t)t * NP];
        c = gv * c + (1.0f - gv) * zv;
        hp[(size_t)t * D_SZ] = ov * c;
    }
}

extern "C" void kernel_launch(void* const* d_in, const int* in_sizes, int n_in,
                              void* d_out, int out_size, void* d_ws, size_t ws_size,
                              hipStream_t stream) {
    const float* gate = (const float*)d_in[0];
    const float* xin  = (const float*)d_in[1];
    const float* Wz   = (const float*)d_in[2];
    const float* bz   = (const float*)d_in[3];
    const float* Wo   = (const float*)d_in[4];
    const float* bo   = (const float*)d_in[5];
    float* out = (float*)d_out;

    char* ws = (char*)d_ws;
    // workspace layout (all offsets 256B-aligned)
    _Float16* Xf16 = (_Float16*)(ws);                       // M*KP*2      = 83,886,080
    _Float16* C16  = (_Float16*)(ws + 83886080ull);         // M*NP*2      = 167,772,160
    _Float16* Wc   = (_Float16*)(ws + 251658240ull);        // NP*KP*2     = 409,600
    float*    bias = (float*)   (ws + 252067840ull);        // NP*4        = 2,560
    float*    Ach  = (float*)   (ws + 252070400ull);        // 64*16*300*4 = 1,228,800
    float*    Bch  = (float*)   (ws + 253299200ull);        // 1,228,800
    float*    Cin  = (float*)   (ws + 254528000ull);        // 1,228,800   (end ~255.8MB)

    pack_x<<<(M_SZ * KP) / 256, 256, 0, stream>>>(xin, Xf16);
    pack_w<<<(NP * KP + 255) / 256, 256, 0, stream>>>(Wz, Wo, Wc);
    pack_bias<<<1, NP, 0, stream>>>(bz, bo, bias);

    gemm_zo<<<(M_SZ / 128) * (NP / 128), 256, 0, stream>>>(Xf16, Wc, bias, C16);

    scan_p1<<<B_SZ * NCHUNK, 320, 0, stream>>>(gate, C16, Ach, Bch);
    scan_p2<<<(B_SZ * D_SZ + 255) / 256, 256, 0, stream>>>(Ach, Bch, Cin);
    scan_p3<<<B_SZ * NCHUNK, 320, 0, stream>>>(gate, C16, Cin, out);
}

// Round 2
// 328.440 us; speedup vs baseline: 1.0457x; 1.0457x over previous
//
#include <hip/hip_runtime.h>
#include <hip/hip_bf16.h>

typedef _Float16 f16x8 __attribute__((ext_vector_type(8)));
typedef _Float16 f16x4 __attribute__((ext_vector_type(4)));
typedef float f32x4 __attribute__((ext_vector_type(4)));

#define B_SZ 64
#define T_SZ 2048
#define D_SZ 300
#define M_SZ (B_SZ * T_SZ)      // 131072
#define KP 320                   // padded K
#define NP 640                   // padded combined N (z: 0..299, o: 320..619)
#define NCHUNK 32
#define CLEN 64                  // T / NCHUNK

__device__ __forceinline__ void gld_lds16(const void* g, void* l) {
    __builtin_amdgcn_global_load_lds(
        (const __attribute__((address_space(1))) unsigned int*)g,
        (__attribute__((address_space(3))) unsigned int*)l,
        16, 0, 0);
}

__device__ __forceinline__ float fast_tanh(float x) {
    float e = __expf(2.0f * x);
    return 1.0f - 2.0f * __builtin_amdgcn_rcpf(e + 1.0f);
}

// ---- pack inputs_encoding fp32 [M,300] -> fp16 [M,320] (k<300 part), float4 reads ----
__global__ void pack_x(const float* __restrict__ in, _Float16* __restrict__ out) {
    unsigned int i = blockIdx.x * 256u + threadIdx.x;  // grid covers M*300/4 exactly
    f32x4 v = *(const f32x4*)(in + (size_t)i * 4);
#pragma unroll
    for (int j = 0; j < 4; ++j) {
        unsigned int f = i * 4 + j;
        unsigned int row = f / D_SZ;
        unsigned int k = f - row * D_SZ;
        out[(size_t)row * KP + k] = (_Float16)v[j];
    }
}

// ---- zero-fill the pad region k in [300,320) ----
__global__ void pad_x(_Float16* __restrict__ out) {
    unsigned int i = blockIdx.x * 256u + threadIdx.x;  // grid covers M*20/4
    unsigned int j = i * 4;
    unsigned int row = j / 20;
    unsigned int k0 = j - row * 20;
    f16x4 z = {};
    *(f16x4*)(out + (size_t)row * KP + 300 + k0) = z;
}

// ---- pack Wz/Wo fp32 [300,300] -> combined fp16 [640,320] ----
__global__ void pack_w(const float* __restrict__ Wz, const float* __restrict__ Wo,
                       _Float16* __restrict__ W) {
    unsigned int i = blockIdx.x * 256u + threadIdx.x;
    if (i >= NP * KP) return;
    unsigned int n = i / KP;
    unsigned int k = i - n * KP;
    float v = 0.0f;
    if (k < D_SZ) {
        if (n < D_SZ) v = Wz[n * D_SZ + k];
        else if (n >= 320 && n < 320 + D_SZ) v = Wo[(n - 320) * D_SZ + k];
    }
    W[i] = (_Float16)v;
}

__global__ void pack_bias(const float* __restrict__ bz, const float* __restrict__ bo,
                          float* __restrict__ bias) {
    int n = threadIdx.x;
    float v = 0.0f;
    if (n < D_SZ) v = bz[n];
    else if (n >= 320 && n < 320 + D_SZ) v = bo[n - 320];
    bias[n] = v;
}

// ---- GEMM: C16[m][n] = tanh( sum_k X[m][k]*W[n][k] + bias[n] ), fp16 out ----
// 256x128 tile, BK=32, 8 waves (4x2), swapped-operand 16x16x32 f16 MFMA so the
// epilogue packs 4 consecutive n per lane -> f16x4 8B stores.
__global__ __launch_bounds__(512) void gemm_zo(const _Float16* __restrict__ X,
                                               const _Float16* __restrict__ W,
                                               const float* __restrict__ bias,
                                               _Float16* __restrict__ C) {
    __shared__ _Float16 As[2][256 * 32];   // 32 KB
    __shared__ _Float16 Bs[2][128 * 32];   // 16 KB

    const int tid = threadIdx.x;
    const int lane = tid & 63;
    const int wid = tid >> 6;              // 0..7
    const int wm = wid >> 1, wn = wid & 1; // 4 x 2 wave grid

    // XCD-aware swizzle (2560 blocks, 2560 % 8 == 0 -> bijective)
    int g = blockIdx.x;
    int s = (g & 7) * (2560 / 8) + (g >> 3);
    int bm = s / 5;          // 512 M-tiles
    int bn = s - bm * 5;     // 5 N-tiles

    f32x4 acc[4][4] = {};

    const int r_in_c = lane >> 2;          // row within 16-row chunk
    const int u_phys = lane & 3;           // 16B unit within 64B row

    auto stage = [&](int buf, int kt) {
        // A: 16 chunks of 16 rows; this wave stages chunks wid, wid+8
#pragma unroll
        for (int j = 0; j < 2; ++j) {
            int c = wid + j * 8;
            int row = c * 16 + r_in_c;
            int ul = u_phys ^ ((row >> 1) & 3);   // inverse-swizzled source unit
            const _Float16* ga = X + ((size_t)(bm * 256 + row) * KP + kt * 32 + ul * 8);
            gld_lds16(ga, &As[buf][c * 512]);
        }
        // B: 8 chunks; this wave stages chunk wid
        {
            int c = wid;
            int row = c * 16 + r_in_c;
            int ul = u_phys ^ ((row >> 1) & 3);
            const _Float16* gb = W + ((size_t)(bn * 128 + row) * KP + kt * 32 + ul * 8);
            gld_lds16(gb, &Bs[buf][c * 512]);
        }
    };

    stage(0, 0);
    __syncthreads();

    int buf = 0;
#pragma unroll 1
    for (int kt = 0; kt < 10; ++kt) {
        if (kt < 9) stage(buf ^ 1, kt + 1);

        f16x8 bf[4];
#pragma unroll
        for (int ns = 0; ns < 4; ++ns) {
            int row = wn * 64 + ns * 16 + (lane & 15);
            int u = (lane >> 4) ^ ((row >> 1) & 3);
            bf[ns] = *(const f16x8*)&Bs[buf][row * 32 + u * 8];
        }
#pragma unroll
        for (int ms = 0; ms < 4; ++ms) {
            int row = wm * 64 + ms * 16 + (lane & 15);
            int u = (lane >> 4) ^ ((row >> 1) & 3);
            f16x8 af = *(const f16x8*)&As[buf][row * 32 + u * 8];
#pragma unroll
            for (int ns = 0; ns < 4; ++ns)
                acc[ms][ns] = __builtin_amdgcn_mfma_f32_16x16x32_f16(bf[ns], af, acc[ms][ns], 0, 0, 0);
        }

        __syncthreads();
        buf ^= 1;
    }

    // epilogue: swapped layout -> lane holds 4 consecutive n at one m.
    // m = mrow0 + ms*16 + (lane&15); n = ncol0 + ns*16 + (lane>>4)*4 + r
    const int mrow0 = bm * 256 + wm * 64;
    const int ncol0 = bn * 128 + wn * 64;
#pragma unroll
    for (int ns = 0; ns < 4; ++ns) {
        int nb = ncol0 + ns * 16 + (lane >> 4) * 4;
        f32x4 b4 = *(const f32x4*)&bias[nb];
#pragma unroll
        for (int ms = 0; ms < 4; ++ms) {
            int m = mrow0 + ms * 16 + (lane & 15);
            f16x4 v;
#pragma unroll
            for (int r = 0; r < 4; ++r)
                v[r] = (_Float16)fast_tanh(acc[ms][ns][r] + b4[r]);
            *(f16x4*)&C[(size_t)m * NP + nb] = v;
        }
    }
}

// ---- scan phase 1: per (b, chunk, d) compute affine (A = prod g, Bc) ----
__global__ void scan_p1(const float* __restrict__ gate, const _Float16* __restrict__ C,
                        float* __restrict__ Aout, float* __restrict__ Bout) {
    int b = blockIdx.x >> 5;
    int nc = blockIdx.x & 31;
    int d = threadIdx.x;
    if (d >= D_SZ) return;
    size_t base = (size_t)b * T_SZ + (size_t)nc * CLEN;
    const float* gp = gate + base * D_SZ + d;
    const _Float16* zp = C + base * NP + d;
    float A = 1.0f, Bc = 0.0f;
    for (int t = 0; t < CLEN; ++t) {
        float gv = gp[(size_t)t * D_SZ];
        float zv = (float)zp[(size_t)t * NP];
        A *= gv;
        Bc = gv * Bc + (1.0f - gv) * zv;
    }
    int o = (b * NCHUNK + nc) * D_SZ + d;
    Aout[o] = A;
    Bout[o] = Bc;
}

// ---- scan phase 2: sequential scan over the 32 chunk summaries ----
__global__ void scan_p2(const float* __restrict__ A, const float* __restrict__ Bc,
                        float* __restrict__ Cin) {
    int idx = blockIdx.x * 256 + threadIdx.x;
    if (idx >= B_SZ * D_SZ) return;
    int b = idx / D_SZ;
    int d = idx - b * D_SZ;
    float c = 0.0f;
    for (int nc = 0; nc < NCHUNK; ++nc) {
        int o = (b * NCHUNK + nc) * D_SZ + d;
        Cin[o] = c;
        c = A[o] * c + Bc[o];
    }
}

// ---- scan phase 3: replay chunk with correct c_in, write h = o * c ----
__global__ void scan_p3(const float* __restrict__ gate, const _Float16* __restrict__ C,
                        const float* __restrict__ Cin, float* __restrict__ out) {
    int b = blockIdx.x >> 5;
    int nc = blockIdx.x & 31;
    int d = threadIdx.x;
    if (d >= D_SZ) return;
    size_t base = (size_t)b * T_SZ + (size_t)nc * CLEN;
    const float* gp = gate + base * D_SZ + d;
    const _Float16* zp = C + base * NP + d;
    const _Float16* op = zp + 320;
    float* hp = out + base * D_SZ + d;
    float c = Cin[(b * NCHUNK + nc) * D_SZ + d];
    for (int t = 0; t < CLEN; ++t) {
        float gv = gp[(size_t)t * D_SZ];
        float zv = (float)zp[(size_t)t * NP];
        float ov = (float)op[(size_t)t * NP];
        c = gv * c + (1.0f - gv) * zv;
        hp[(size_t)t * D_SZ] = ov * c;
    }
}

extern "C" void kernel_launch(void* const* d_in, const int* in_sizes, int n_in,
                              void* d_out, int out_size, void* d_ws, size_t ws_size,
                              hipStream_t stream) {
    const float* gate = (const float*)d_in[0];
    const float* xin  = (const float*)d_in[1];
    const float* Wz   = (const float*)d_in[2];
    const float* bz   = (const float*)d_in[3];
    const float* Wo   = (const float*)d_in[4];
    const float* bo   = (const float*)d_in[5];
    float* out = (float*)d_out;

    char* ws = (char*)d_ws;
    // workspace layout: Xf16 region is reused by scan summaries after the GEMM.
    _Float16* Xf16 = (_Float16*)(ws);                       // M*KP*2      = 83,886,080
    _Float16* C16  = (_Float16*)(ws + 83886080ull);         // M*NP*2      = 167,772,160
    _Float16* Wc   = (_Float16*)(ws + 251658240ull);        // NP*KP*2     = 409,600
    float*    bias = (float*)   (ws + 252067840ull);        // NP*4        = 2,560
    float*    Ach  = (float*)   (ws);                       // 64*32*300*4 = 2,457,600 (reuses Xf16)
    float*    Bch  = (float*)   (ws + 2457600ull);          // 2,457,600
    float*    Cin  = (float*)   (ws + 4915200ull);          // 2,457,600

    pack_x<<<(M_SZ * D_SZ / 4) / 256, 256, 0, stream>>>(xin, Xf16);
    pad_x<<<(M_SZ * 20 / 4) / 256, 256, 0, stream>>>(Xf16);
    pack_w<<<(NP * KP + 255) / 256, 256, 0, stream>>>(Wz, Wo, Wc);
    pack_bias<<<1, NP, 0, stream>>>(bz, bo, bias);

    gemm_zo<<<(M_SZ / 256) * (NP / 128), 512, 0, stream>>>(Xf16, Wc, bias, C16);

    scan_p1<<<B_SZ * NCHUNK, 320, 0, stream>>>(gate, C16, Ach, Bch);
    scan_p2<<<(B_SZ * D_SZ + 255) / 256, 256, 0, stream>>>(Ach, Bch, Cin);
    scan_p3<<<B_SZ * NCHUNK, 320, 0, stream>>>(gate, C16, Cin, out);
}

// Round 3
// 327.422 us; speedup vs baseline: 1.0489x; 1.0031x over previous
//
#include <hip/hip_runtime.h>
#include <hip/hip_bf16.h>

typedef _Float16 f16x8 __attribute__((ext_vector_type(8)));
typedef _Float16 f16x4 __attribute__((ext_vector_type(4)));
typedef float f32x4 __attribute__((ext_vector_type(4)));

#define B_SZ 64
#define T_SZ 2048
#define D_SZ 300
#define M_SZ (B_SZ * T_SZ)      // 131072
#define KP 320                   // padded K
#define NP 640                   // padded combined N (z: 0..299, o: 320..619)
#define NCHUNK 32
#define CLEN 64                  // T / NCHUNK

__device__ __forceinline__ void gld_lds16(const void* g, void* l) {
    __builtin_amdgcn_global_load_lds(
        (const __attribute__((address_space(1))) unsigned int*)g,
        (__attribute__((address_space(3))) unsigned int*)l,
        16, 0, 0);
}

__device__ __forceinline__ float fast_tanh(float x) {
    float e = __expf(2.0f * x);
    return 1.0f - 2.0f * __builtin_amdgcn_rcpf(e + 1.0f);
}

// ---- pack inputs_encoding fp32 [M,300] -> fp16 [M,320] (k<300 part), float4 reads ----
__global__ void pack_x(const float* __restrict__ in, _Float16* __restrict__ out) {
    unsigned int i = blockIdx.x * 256u + threadIdx.x;  // grid covers M*300/4 exactly
    f32x4 v = *(const f32x4*)(in + (size_t)i * 4);
#pragma unroll
    for (int j = 0; j < 4; ++j) {
        unsigned int f = i * 4 + j;
        unsigned int row = f / D_SZ;
        unsigned int k = f - row * D_SZ;
        out[(size_t)row * KP + k] = (_Float16)v[j];
    }
}

// ---- zero-fill the pad region k in [300,320) ----
__global__ void pad_x(_Float16* __restrict__ out) {
    unsigned int i = blockIdx.x * 256u + threadIdx.x;  // grid covers M*20/4
    unsigned int j = i * 4;
    unsigned int row = j / 20;
    unsigned int k0 = j - row * 20;
    f16x4 z = {};
    *(f16x4*)(out + (size_t)row * KP + 300 + k0) = z;
}

// ---- pack Wz/Wo fp32 [300,300] -> combined fp16 [640,320] ----
__global__ void pack_w(const float* __restrict__ Wz, const float* __restrict__ Wo,
                       _Float16* __restrict__ W) {
    unsigned int i = blockIdx.x * 256u + threadIdx.x;
    if (i >= NP * KP) return;
    unsigned int n = i / KP;
    unsigned int k = i - n * KP;
    float v = 0.0f;
    if (k < D_SZ) {
        if (n < D_SZ) v = Wz[n * D_SZ + k];
        else if (n >= 320 && n < 320 + D_SZ) v = Wo[(n - 320) * D_SZ + k];
    }
    W[i] = (_Float16)v;
}

__global__ void pack_bias(const float* __restrict__ bz, const float* __restrict__ bo,
                          float* __restrict__ bias) {
    int n = threadIdx.x;
    float v = 0.0f;
    if (n < D_SZ) v = bz[n];
    else if (n >= 320 && n < 320 + D_SZ) v = bo[n - 320];
    bias[n] = v;
}

// ---- GEMM: C16[m][n] = tanh( sum_k X[m][k]*W[n][k] + bias[n] ), fp16 out ----
// 128x128 tile, BK=32, 4 waves (2x2). 3-buffer LDS, 2-deep global_load_lds
// prefetch, raw s_barrier + counted vmcnt (T3+T4), setprio around MFMA (T5).
__global__ __launch_bounds__(256) void gemm_zo(const _Float16* __restrict__ X,
                                               const _Float16* __restrict__ W,
                                               const float* __restrict__ bias,
                                               _Float16* __restrict__ C) {
    __shared__ _Float16 As[3][128 * 32];   // 24 KB
    __shared__ _Float16 Bs[3][128 * 32];   // 24 KB

    const int tid = threadIdx.x;
    const int lane = tid & 63;
    const int wid = tid >> 6;              // 0..3
    const int wm = wid >> 1, wn = wid & 1;

    // XCD-aware swizzle (5120 blocks, 5120 % 8 == 0 -> bijective)
    int g = blockIdx.x;
    int s = (g & 7) * (5120 / 8) + (g >> 3);
    int bm = s / 5;          // 1024 M-tiles
    int bn = s - bm * 5;     // 5 N-tiles

    f32x4 acc[4][4] = {};

    const int r_in_c = lane >> 2;          // row within 16-row chunk
    const int u_phys = lane & 3;           // 16B unit within 64B row

    const _Float16* Abase = X + (size_t)(bm * 128) * KP;
    const _Float16* Bbase = W + (size_t)(bn * 128) * KP;

    auto stage = [&](int buf, int kt) {
        // A and B each: 8 chunks of 16 rows; wave stages chunks wid, wid+4
#pragma unroll
        for (int j = 0; j < 2; ++j) {
            int c = wid + j * 4;
            int row = c * 16 + r_in_c;
            int ul = u_phys ^ ((row >> 1) & 3);   // inverse-swizzled source unit
            gld_lds16(Abase + (size_t)row * KP + kt * 32 + ul * 8, &As[buf][c * 512]);
            gld_lds16(Bbase + (size_t)row * KP + kt * 32 + ul * 8, &Bs[buf][c * 512]);
        }
    };

    stage(0, 0);
    stage(1, 1);

#pragma unroll 1
    for (int kt = 0; kt < 10; ++kt) {
        // Stage 2 ahead into buf (kt+2)%3 == (kt-1)%3, released by last iter's
        // read-done barrier.
        if (kt < 8) {
            stage((kt + 2) % 3, kt + 2);
            asm volatile("s_waitcnt vmcnt(8)" ::: "memory");   // kt's 4 loads landed
        } else if (kt == 8) {
            asm volatile("s_waitcnt vmcnt(4)" ::: "memory");
        } else {
            asm volatile("s_waitcnt vmcnt(0)" ::: "memory");
        }
        __builtin_amdgcn_s_barrier();          // all waves' loads for kt landed
        __builtin_amdgcn_sched_barrier(0);

        const int cb = kt % 3;
        f16x8 bf[4], af[4];
#pragma unroll
        for (int ns = 0; ns < 4; ++ns) {
            int row = wn * 64 + ns * 16 + (lane & 15);
            int u = (lane >> 4) ^ ((row >> 1) & 3);
            bf[ns] = *(const f16x8*)&Bs[cb][row * 32 + u * 8];
        }
#pragma unroll
        for (int ms = 0; ms < 4; ++ms) {
            int row = wm * 64 + ms * 16 + (lane & 15);
            int u = (lane >> 4) ^ ((row >> 1) & 3);
            af[ms] = *(const f16x8*)&As[cb][row * 32 + u * 8];
        }
        asm volatile("s_waitcnt lgkmcnt(0)" ::: "memory");  // frags in regs
        __builtin_amdgcn_s_barrier();          // release buf cb for overwrite
        __builtin_amdgcn_sched_barrier(0);

        __builtin_amdgcn_s_setprio(1);
#pragma unroll
        for (int ms = 0; ms < 4; ++ms)
#pragma unroll
            for (int ns = 0; ns < 4; ++ns)
                acc[ms][ns] = __builtin_amdgcn_mfma_f32_16x16x32_f16(bf[ns], af[ms], acc[ms][ns], 0, 0, 0);
        __builtin_amdgcn_s_setprio(0);
    }

    // epilogue: swapped layout -> lane holds 4 consecutive n at one m.
    // m = mrow0 + ms*16 + (lane&15); n = ncol0 + ns*16 + (lane>>4)*4 + r
    const int mrow0 = bm * 128 + wm * 64;
    const int ncol0 = bn * 128 + wn * 64;
#pragma unroll
    for (int ns = 0; ns < 4; ++ns) {
        int nb = ncol0 + ns * 16 + (lane >> 4) * 4;
        f32x4 b4 = *(const f32x4*)&bias[nb];
#pragma unroll
        for (int ms = 0; ms < 4; ++ms) {
            int m = mrow0 + ms * 16 + (lane & 15);
            f16x4 v;
#pragma unroll
            for (int r = 0; r < 4; ++r)
                v[r] = (_Float16)fast_tanh(acc[ms][ns][r] + b4[r]);
            *(f16x4*)&C[(size_t)m * NP + nb] = v;
        }
    }
}

// ---- scan phase 1: per (b, chunk, d) compute affine (A = prod g, Bc) ----
__global__ void scan_p1(const float* __restrict__ gate, const _Float16* __restrict__ C,
                        float* __restrict__ Aout, float* __restrict__ Bout) {
    int b = blockIdx.x >> 5;
    int nc = blockIdx.x & 31;
    int d = threadIdx.x;
    if (d >= D_SZ) return;
    size_t base = (size_t)b * T_SZ + (size_t)nc * CLEN;
    const float* gp = gate + base * D_SZ + d;
    const _Float16* zp = C + base * NP + d;
    float A = 1.0f, Bc = 0.0f;
    for (int t = 0; t < CLEN; ++t) {
        float gv = gp[(size_t)t * D_SZ];
        float zv = (float)zp[(size_t)t * NP];
        A *= gv;
        Bc = gv * Bc + (1.0f - gv) * zv;
    }
    int o = (b * NCHUNK + nc) * D_SZ + d;
    Aout[o] = A;
    Bout[o] = Bc;
}

// ---- scan phase 2: sequential scan over the 32 chunk summaries ----
__global__ void scan_p2(const float* __restrict__ A, const float* __restrict__ Bc,
                        float* __restrict__ Cin) {
    int idx = blockIdx.x * 256 + threadIdx.x;
    if (idx >= B_SZ * D_SZ) return;
    int b = idx / D_SZ;
    int d = idx - b * D_SZ;
    float c = 0.0f;
    for (int nc = 0; nc < NCHUNK; ++nc) {
        int o = (b * NCHUNK + nc) * D_SZ + d;
        Cin[o] = c;
        c = A[o] * c + Bc[o];
    }
}

// ---- scan phase 3: replay chunk with correct c_in, write h = o * c ----
__global__ void scan_p3(const float* __restrict__ gate, const _Float16* __restrict__ C,
                        const float* __restrict__ Cin, float* __restrict__ out) {
    int b = blockIdx.x >> 5;
    int nc = blockIdx.x & 31;
    int d = threadIdx.x;
    if (d >= D_SZ) return;
    size_t base = (size_t)b * T_SZ + (size_t)nc * CLEN;
    const float* gp = gate + base * D_SZ + d;
    const _Float16* zp = C + base * NP + d;
    const _Float16* op = zp + 320;
    float* hp = out + base * D_SZ + d;
    float c = Cin[(b * NCHUNK + nc) * D_SZ + d];
    for (int t = 0; t < CLEN; ++t) {
        float gv = gp[(size_t)t * D_SZ];
        float zv = (float)zp[(size_t)t * NP];
        float ov = (float)op[(size_t)t * NP];
        c = gv * c + (1.0f - gv) * zv;
        hp[(size_t)t * D_SZ] = ov * c;
    }
}

extern "C" void kernel_launch(void* const* d_in, const int* in_sizes, int n_in,
                              void* d_out, int out_size, void* d_ws, size_t ws_size,
                              hipStream_t stream) {
    const float* gate = (const float*)d_in[0];
    const float* xin  = (const float*)d_in[1];
    const float* Wz   = (const float*)d_in[2];
    const float* bz   = (const float*)d_in[3];
    const float* Wo   = (const float*)d_in[4];
    const float* bo   = (const float*)d_in[5];
    float* out = (float*)d_out;

    char* ws = (char*)d_ws;
    // workspace layout: Xf16 region is reused by scan summaries after the GEMM.
    _Float16* Xf16 = (_Float16*)(ws);                       // M*KP*2      = 83,886,080
    _Float16* C16  = (_Float16*)(ws + 83886080ull);         // M*NP*2      = 167,772,160
    _Float16* Wc   = (_Float16*)(ws + 251658240ull);        // NP*KP*2     = 409,600
    float*    bias = (float*)   (ws + 252067840ull);        // NP*4        = 2,560
    float*    Ach  = (float*)   (ws);                       // 64*32*300*4 = 2,457,600 (reuses Xf16)
    float*    Bch  = (float*)   (ws + 2457600ull);          // 2,457,600
    float*    Cin  = (float*)   (ws + 4915200ull);          // 2,457,600

    pack_x<<<(M_SZ * D_SZ / 4) / 256, 256, 0, stream>>>(xin, Xf16);
    pad_x<<<(M_SZ * 20 / 4) / 256, 256, 0, stream>>>(Xf16);
    pack_w<<<(NP * KP + 255) / 256, 256, 0, stream>>>(Wz, Wo, Wc);
    pack_bias<<<1, NP, 0, stream>>>(bz, bo, bias);

    gemm_zo<<<(M_SZ / 128) * (NP / 128), 256, 0, stream>>>(Xf16, Wc, bias, C16);

    scan_p1<<<B_SZ * NCHUNK, 320, 0, stream>>>(gate, C16, Ach, Bch);
    scan_p2<<<(B_SZ * D_SZ + 255) / 256, 256, 0, stream>>>(Ach, Bch, Cin);
    scan_p3<<<B_SZ * NCHUNK, 320, 0, stream>>>(gate, C16, Cin, out);
}